// Round 2
// baseline (681.435 us; speedup 1.0000x reference)
//
#include <hip/hip_runtime.h>

#define S_LEN   2048
#define HID     4096
#define NHEADS  32
#define NKVH    8
#define HDIM    128
#define NQKV    6144          // NKV*(QPK+2)*HD = 8*6*128
#define ATT_SCALE (1.0f/128.0f)

typedef unsigned short u16;
typedef __attribute__((ext_vector_type(8))) __bf16 bf16x8;
typedef __attribute__((ext_vector_type(4))) float  f32x4;

__device__ __forceinline__ u16 f2bf(float f) {
    union { float f; unsigned u; } x; x.f = f;
    unsigned u = x.u;
    u += 0x7fffu + ((u >> 16) & 1u);   // round-to-nearest-even
    return (u16)(u >> 16);
}
__device__ __forceinline__ float bf2f(u16 v) {
    union { unsigned u; float f; } x; x.u = ((unsigned)v) << 16; return x.f;
}

// ---------------- fp32 -> bf16 conversion ----------------
__global__ __launch_bounds__(256) void cvt_bf16_kernel(const float* __restrict__ in,
                                                       u16* __restrict__ out, int n4) {
    int stride = gridDim.x * blockDim.x;
    for (int i = blockIdx.x * blockDim.x + threadIdx.x; i < n4; i += stride) {
        float4 v = *(const float4*)(in + (size_t)i * 4);
        ushort4 o = make_ushort4(f2bf(v.x), f2bf(v.y), f2bf(v.z), f2bf(v.w));
        *(ushort4*)(out + (size_t)i * 4) = o;
    }
}

// ---------------- bf16 GEMM:  C(MxN) = A(MxK) * B(NxK)^T + bias(N) ----------------
// m97 structure: 128x128 tile, BK=64, global_load_lds width=16 into UNPADDED LDS,
// 4 waves each computing 64x64 via 4x4 grid of 16x16x32 MFMA.
#define BM 128
#define BN 128
#define BK 64

template <bool OUT_BF16>
__global__ __launch_bounds__(256) void gemm_bt_kernel(
    const u16* __restrict__ A,   // M x K  bf16
    const u16* __restrict__ B,   // N x K  bf16
    const float* __restrict__ bias, // N
    void* __restrict__ Cout,     // M x N  (fp32 or bf16)
    int M, int N, int K)
{
    __shared__ u16 Alds[BM][BK];   // unpadded: row = 128 B, required by global_load_lds
    __shared__ u16 Blds[BN][BK];

    const int tid  = threadIdx.x;
    const int wid  = tid >> 6;
    const int lane = tid & 63;
    const int ln   = lane & 15;
    const int quad = lane >> 4;
    const int wm   = (wid >> 1) * 64;
    const int wn   = (wid & 1) * 64;
    const int tileM = blockIdx.y * BM;
    const int tileN = blockIdx.x * BN;

    // staging coords: wave covers 8 rows (64 lanes x 16 B = 1024 B = 8 x 128 B rows)
    const int lrow = lane >> 3;        // 0..7
    const int lcol = (lane & 7) * 8;   // 0..56 step 8 (elems)

    f32x4 acc[4][4];
    #pragma unroll
    for (int i = 0; i < 4; i++)
        #pragma unroll
        for (int j = 0; j < 4; j++) {
            f32x4 z = {0.f, 0.f, 0.f, 0.f};
            acc[i][j] = z;
        }

    for (int k0 = 0; k0 < K; k0 += BK) {
        __syncthreads();    // previous tile's LDS reads done
        #pragma unroll
        for (int p = 0; p < 4; p++) {
            int r = p * 32 + wid * 8;                        // wave-uniform row base
            const u16* ga = A + (size_t)(tileM + r + lrow) * K + k0 + lcol;
            const u16* gb = B + (size_t)(tileN + r + lrow) * K + k0 + lcol;
            __builtin_amdgcn_global_load_lds(
                (const __attribute__((address_space(1))) void*)ga,
                (__attribute__((address_space(3))) void*)&Alds[r][0], 16, 0, 0);
            __builtin_amdgcn_global_load_lds(
                (const __attribute__((address_space(1))) void*)gb,
                (__attribute__((address_space(3))) void*)&Blds[r][0], 16, 0, 0);
        }
        __syncthreads();    // drains vmcnt -> tiles resident

        #pragma unroll
        for (int kk = 0; kk < BK; kk += 32) {
            bf16x8 af[4], bfr[4];
            #pragma unroll
            for (int i = 0; i < 4; i++)
                af[i] = *(const bf16x8*)(&Alds[wm + i * 16 + ln][kk + quad * 8]);
            #pragma unroll
            for (int j = 0; j < 4; j++)
                bfr[j] = *(const bf16x8*)(&Blds[wn + j * 16 + ln][kk + quad * 8]);
            #pragma unroll
            for (int i = 0; i < 4; i++)
                #pragma unroll
                for (int j = 0; j < 4; j++)
                    acc[i][j] = __builtin_amdgcn_mfma_f32_16x16x32_bf16(af[i], bfr[j], acc[i][j], 0, 0, 0);
        }
    }

    #pragma unroll
    for (int i = 0; i < 4; i++) {
        #pragma unroll
        for (int j = 0; j < 4; j++) {
            int n = tileN + wn + j * 16 + ln;
            float bv = bias[n];
            #pragma unroll
            for (int r = 0; r < 4; r++) {
                int m = tileM + wm + i * 16 + quad * 4 + r;
                float v = acc[i][j][r] + bv;
                if (OUT_BF16)
                    ((u16*)Cout)[(size_t)m * N + n] = f2bf(v);
                else
                    ((float*)Cout)[(size_t)m * N + n] = v;
            }
        }
    }
}

// ---------------- RoPE + split qkv (bf16 in, bf16 out) ----------------
// qkv bf16 (S, NQKV) laid out per position as (NKV=8, 6, 128): [q0..q3, k, v].
__global__ __launch_bounds__(128) void rope_split_kernel(
    const u16* __restrict__ qkv, const int* __restrict__ positions,
    u16* __restrict__ qb_o, u16* __restrict__ kb_o, u16* __restrict__ vb_o)
{
    const int d   = threadIdx.x;     // 0..127
    const int pos = blockIdx.x;      // 0..S-1
    const int hy  = blockIdx.y;      // 0..47
    const float p = (float)positions[pos];

    if (hy >= NHEADS + NKVH) {               // v copy
        int kv = hy - NHEADS - NKVH;
        const u16* src = qkv + (size_t)pos * NQKV + (kv * 6 + 5) * HDIM;
        vb_o[((size_t)kv * S_LEN + pos) * HDIM + d] = src[d];
        return;
    }
    const u16* src;
    u16* dst;
    if (hy < NHEADS) {                        // q head
        int kv = hy >> 2, qi = hy & 3;
        src = qkv + (size_t)pos * NQKV + (kv * 6 + qi) * HDIM;
        dst = qb_o + ((size_t)hy * S_LEN + pos) * HDIM;
    } else {                                  // k head
        int kv = hy - NHEADS;
        src = qkv + (size_t)pos * NQKV + (kv * 6 + 4) * HDIM;
        dst = kb_o + ((size_t)kv * S_LEN + pos) * HDIM;
    }
    int d2 = d & 63;
    float inv = expf(-(float)d2 * (13.815510557964274f / 64.0f)); // 1e6^(-d2/64)
    float fr = p * inv;
    float s, c;
    sincosf(fr, &s, &c);
    float x1 = bf2f(src[d2]);
    float x2 = bf2f(src[d2 + 64]);
    float o = (d < 64) ? (x1 * c - x2 * s) : (x2 * c + x1 * s);
    dst[d] = f2bf(o);
}

// ---------------- blocksparse flash attention ----------------
// grid (S/64, NH); block 256 (4 waves). Wave w owns query rows w*16..w*16+15.
#define LDK 136   // 128+8
#define LDV 72    // 64+8
__global__ __launch_bounds__(256) void attn_bs_kernel(
    const u16* __restrict__ Q,   // (NH, S, HD) bf16
    const u16* __restrict__ K,   // (NKV, S, HD)
    const u16* __restrict__ V,   // (NKV, S, HD)
    u16* __restrict__ O)         // (S, NH*HD) bf16
{
    __shared__ u16 Qs[64][LDK];
    __shared__ u16 Ks[64][LDK];
    __shared__ u16 Vt[128][LDV];
    __shared__ u16 Ps[4][16][LDV];

    const int qb = blockIdx.x;
    const int h  = blockIdx.y;
    const int kv = h >> 2;
    const int tid  = threadIdx.x;
    const int w    = tid >> 6;
    const int lane = tid & 63;
    const int ln   = lane & 15;
    const int quad = lane >> 4;

    // stage Q tile (64 x 128)
    const u16* Qg = Q + ((size_t)h * S_LEN + qb * 64) * HDIM;
    {
        int col = (tid & 15) * 8;
        #pragma unroll
        for (int p = 0; p < 4; p++) {
            int row = p * 16 + (tid >> 4);
            *(uint4*)(&Qs[row][col]) = *(const uint4*)(Qg + row * HDIM + col);
        }
    }

    f32x4 oacc[8];
    #pragma unroll
    for (int n = 0; n < 8; n++) { f32x4 z = {0.f,0.f,0.f,0.f}; oacc[n] = z; }
    float mrow[4] = {-1e30f, -1e30f, -1e30f, -1e30f};
    float lrow[4] = {0.f, 0.f, 0.f, 0.f};

    for (int kb = 0; kb <= qb; kb++) {
        bool sel = (qb - kb < 16) || (((kb + h + 1) & 7) == 0);
        if (!sel) continue;

        __syncthreads();   // protect previous iteration's LDS reads
        const u16* Kg = K + ((size_t)kv * S_LEN + kb * 64) * HDIM;
        const u16* Vg = V + ((size_t)kv * S_LEN + kb * 64) * HDIM;
        {
            int col = (tid & 15) * 8;
            #pragma unroll
            for (int p = 0; p < 4; p++) {
                int row = p * 16 + (tid >> 4);
                *(uint4*)(&Ks[row][col]) = *(const uint4*)(Kg + row * HDIM + col);
            }
            // V staged transposed: Vt[dim][key]
            int key = tid & 63;
            int dbase = (tid >> 6) * 32;
            #pragma unroll
            for (int p = 0; p < 4; p++) {
                int d0 = dbase + p * 8;
                uint4 vv = *(const uint4*)(Vg + key * HDIM + d0);
                const u16* pv = (const u16*)&vv;
                #pragma unroll
                for (int jj = 0; jj < 8; jj++) Vt[d0 + jj][key] = pv[jj];
            }
        }
        __syncthreads();

        // S = Q K^T  (wave's 16 rows x 64 keys)
        f32x4 sacc[4];
        #pragma unroll
        for (int jj = 0; jj < 4; jj++) { f32x4 z = {0.f,0.f,0.f,0.f}; sacc[jj] = z; }
        #pragma unroll
        for (int ks = 0; ks < 4; ks++) {
            bf16x8 aq = *(const bf16x8*)(&Qs[w * 16 + ln][ks * 32 + quad * 8]);
            #pragma unroll
            for (int jj = 0; jj < 4; jj++) {
                bf16x8 bk = *(const bf16x8*)(&Ks[jj * 16 + ln][ks * 32 + quad * 8]);
                sacc[jj] = __builtin_amdgcn_mfma_f32_16x16x32_bf16(aq, bk, sacc[jj], 0, 0, 0);
            }
        }

        // scale + diagonal causal mask + online softmax; write P to LDS
        #pragma unroll
        for (int r = 0; r < 4; r++) {
            float pv[4];
            float mx = -1e30f;
            const int qrow = w * 16 + quad * 4 + r;
            #pragma unroll
            for (int jj = 0; jj < 4; jj++) {
                float s = sacc[jj][r] * ATT_SCALE;
                if (kb == qb && (jj * 16 + ln) > qrow) s = -1e30f;
                pv[jj] = s;
                mx = fmaxf(mx, s);
            }
            #pragma unroll
            for (int off = 1; off < 16; off <<= 1)
                mx = fmaxf(mx, __shfl_xor(mx, off, 64));
            float mnew  = fmaxf(mrow[r], mx);
            float alpha = __expf(mrow[r] - mnew);
            float sum = 0.f;
            #pragma unroll
            for (int jj = 0; jj < 4; jj++) {
                float pe = __expf(pv[jj] - mnew);
                pv[jj] = pe;
                sum += pe;
            }
            #pragma unroll
            for (int off = 1; off < 16; off <<= 1)
                sum += __shfl_xor(sum, off, 64);
            lrow[r] = lrow[r] * alpha + sum;
            mrow[r] = mnew;
            #pragma unroll
            for (int n = 0; n < 8; n++) oacc[n][r] *= alpha;
            #pragma unroll
            for (int jj = 0; jj < 4; jj++)
                Ps[w][quad * 4 + r][jj * 16 + ln] = f2bf(pv[jj]);
        }
        __syncthreads();   // P LDS round-trip visibility

        // O += P V   (P: 16x64 A-layout; V via Vt: B[n=dim][k=key])
        #pragma unroll
        for (int kk = 0; kk < 2; kk++) {
            bf16x8 ap = *(const bf16x8*)(&Ps[w][ln][kk * 32 + quad * 8]);
            #pragma unroll
            for (int n = 0; n < 8; n++) {
                bf16x8 bv = *(const bf16x8*)(&Vt[n * 16 + ln][kk * 32 + quad * 8]);
                oacc[n] = __builtin_amdgcn_mfma_f32_16x16x32_bf16(ap, bv, oacc[n], 0, 0, 0);
            }
        }
    }

    // epilogue: O /= l, store bf16 (S, NH*HD)
    #pragma unroll
    for (int n = 0; n < 8; n++) {
        #pragma unroll
        for (int r = 0; r < 4; r++) {
            int row = w * 16 + quad * 4 + r;
            int pos = qb * 64 + row;
            float o = oacc[n][r] / lrow[r];
            O[(size_t)pos * (NHEADS * HDIM) + h * HDIM + n * 16 + ln] = f2bf(o);
        }
    }
}

// ---------------- launch ----------------
extern "C" void kernel_launch(void* const* d_in, const int* in_sizes, int n_in,
                              void* d_out, int out_size, void* d_ws, size_t ws_size,
                              hipStream_t stream) {
    const int*   positions = (const int*)d_in[0];
    const float* hidden    = (const float*)d_in[1];
    const float* w_qkv     = (const float*)d_in[2];
    const float* b_qkv     = (const float*)d_in[3];
    const float* w_dense   = (const float*)d_in[4];
    const float* b_dense   = (const float*)d_in[5];
    float* out = (float*)d_out;

    char* ws = (char*)d_ws;
    u16* ws_h    = (u16*)(ws);                    // 2048*4096*2   = 16,777,216
    u16* ws_wqkv = (u16*)(ws + 16777216);         // 6144*4096*2  = 50,331,648
    u16* ws_wd   = (u16*)(ws + 67108864);         // 4096*4096*2  = 33,554,432
    u16* ws_qkv  = (u16*)(ws + 100663296);        // 2048*6144*2  = 25,165,824 (bf16 now)
    u16* ws_q    = (u16*)(ws + 125829120);        // 32*2048*128*2= 16,777,216
    u16* ws_k    = (u16*)(ws + 142606336);        // 8*2048*128*2 =  4,194,304
    u16* ws_v    = (u16*)(ws + 146800640);        //               =  4,194,304
    u16* ws_attn = (u16*)(ws + 150994944);        // 2048*4096*2  = 16,777,216

    cvt_bf16_kernel<<<1024, 256, 0, stream>>>(hidden,  ws_h,    (S_LEN * HID) / 4);
    cvt_bf16_kernel<<<2048, 256, 0, stream>>>(w_qkv,   ws_wqkv, (NQKV * HID) / 4);
    cvt_bf16_kernel<<<2048, 256, 0, stream>>>(w_dense, ws_wd,   (HID * HID) / 4);

    gemm_bt_kernel<true><<<dim3(NQKV / BN, S_LEN / BM), 256, 0, stream>>>(
        ws_h, ws_wqkv, b_qkv, ws_qkv, S_LEN, NQKV, HID);

    rope_split_kernel<<<dim3(S_LEN, NHEADS + 2 * NKVH), 128, 0, stream>>>(
        ws_qkv, positions, ws_q, ws_k, ws_v);

    attn_bs_kernel<<<dim3(S_LEN / 64, NHEADS), 256, 0, stream>>>(ws_q, ws_k, ws_v, ws_attn);

    gemm_bt_kernel<false><<<dim3(HID / BN, S_LEN / BM), 256, 0, stream>>>(
        ws_attn, ws_wd, b_dense, out, S_LEN, HID, HID);
}

// Round 3
// 638.401 us; speedup vs baseline: 1.0674x; 1.0674x over previous
//
#include <hip/hip_runtime.h>

#define S_LEN   2048
#define HID     4096
#define NHEADS  32
#define NKVH    8
#define HDIM    128
#define NQKV    6144          // NKV*(QPK+2)*HD = 8*6*128
#define ATT_SCALE (1.0f/128.0f)

typedef unsigned short u16;
typedef __attribute__((ext_vector_type(8))) __bf16 bf16x8;
typedef __attribute__((ext_vector_type(4))) float  f32x4;

__device__ __forceinline__ u16 f2bf(float f) {
    union { float f; unsigned u; } x; x.f = f;
    unsigned u = x.u;
    u += 0x7fffu + ((u >> 16) & 1u);   // round-to-nearest-even
    return (u16)(u >> 16);
}
__device__ __forceinline__ float bf2f(u16 v) {
    union { unsigned u; float f; } x; x.u = ((unsigned)v) << 16; return x.f;
}

// ---------------- fp32 -> bf16 conversion ----------------
__global__ __launch_bounds__(256) void cvt_bf16_kernel(const float* __restrict__ in,
                                                       u16* __restrict__ out, int n4) {
    int stride = gridDim.x * blockDim.x;
    for (int i = blockIdx.x * blockDim.x + threadIdx.x; i < n4; i += stride) {
        float4 v = *(const float4*)(in + (size_t)i * 4);
        ushort4 o = make_ushort4(f2bf(v.x), f2bf(v.y), f2bf(v.z), f2bf(v.w));
        *(ushort4*)(out + (size_t)i * 4) = o;
    }
}

// ---------------- bf16 GEMM:  C(MxN) = A(MxK) * B(NxK)^T + bias(N) ----------------
// m97 structure + XOR swizzle: 128x128 tile, BK=64, global_load_lds width=16 into
// unpadded LDS with chunk swizzle (physical_chunk = logical_chunk ^ (row & 7)).
// 4 waves each computing 64x64 via 4x4 grid of 16x16x32 MFMA.
#define BM 128
#define BN 128
#define BK 64

template <bool OUT_BF16>
__global__ __launch_bounds__(256) void gemm_bt_kernel(
    const u16* __restrict__ A,   // M x K  bf16
    const u16* __restrict__ B,   // N x K  bf16
    const float* __restrict__ bias, // N
    void* __restrict__ Cout,     // M x N  (fp32 or bf16)
    int M, int N, int K)
{
    __shared__ u16 Alds[BM][BK];   // unpadded rows (128 B); bank spread via XOR swizzle
    __shared__ u16 Blds[BN][BK];

    const int tid  = threadIdx.x;
    const int wid  = tid >> 6;
    const int lane = tid & 63;
    const int ln   = lane & 15;
    const int quad = lane >> 4;
    const int wm   = (wid >> 1) * 64;
    const int wn   = (wid & 1) * 64;
    const int tileM = blockIdx.y * BM;
    const int tileN = blockIdx.x * BN;

    // staging coords: wave covers 8 rows (64 lanes x 16 B = 1024 B = 8 x 128 B rows).
    // lane lands at physical chunk (lane&7) of row (base+lane>>3); to place logical
    // chunk g at physical g^(row&7), lane must FETCH logical chunk (lane&7)^(lane>>3).
    const int lrow = lane >> 3;                    // 0..7
    const int lcol = (((lane & 7) ^ lrow)) * 8;    // swizzled source column (elems)

    f32x4 acc[4][4];
    #pragma unroll
    for (int i = 0; i < 4; i++)
        #pragma unroll
        for (int j = 0; j < 4; j++) {
            f32x4 z = {0.f, 0.f, 0.f, 0.f};
            acc[i][j] = z;
        }

    const int lnx = ln & 7;   // read-side swizzle key (row & 7 == ln & 7)

    for (int k0 = 0; k0 < K; k0 += BK) {
        __syncthreads();    // previous tile's LDS reads done
        #pragma unroll
        for (int p = 0; p < 4; p++) {
            int r = p * 32 + wid * 8;                        // wave-uniform row base
            const u16* ga = A + (size_t)(tileM + r + lrow) * K + k0 + lcol;
            const u16* gb = B + (size_t)(tileN + r + lrow) * K + k0 + lcol;
            __builtin_amdgcn_global_load_lds(
                (const __attribute__((address_space(1))) void*)ga,
                (__attribute__((address_space(3))) void*)&Alds[r][0], 16, 0, 0);
            __builtin_amdgcn_global_load_lds(
                (const __attribute__((address_space(1))) void*)gb,
                (__attribute__((address_space(3))) void*)&Blds[r][0], 16, 0, 0);
        }
        __syncthreads();    // drains vmcnt -> tiles resident

        #pragma unroll
        for (int kk = 0; kk < BK; kk += 32) {
            const int kq = (kk >> 3) + quad;              // logical chunk 0..7
            const int pc = (kq ^ lnx) * 8;                // physical column (elems)
            bf16x8 af[4], bfr[4];
            #pragma unroll
            for (int i = 0; i < 4; i++)
                af[i] = *(const bf16x8*)(&Alds[wm + i * 16 + ln][pc]);
            #pragma unroll
            for (int j = 0; j < 4; j++)
                bfr[j] = *(const bf16x8*)(&Blds[wn + j * 16 + ln][pc]);
            #pragma unroll
            for (int i = 0; i < 4; i++)
                #pragma unroll
                for (int j = 0; j < 4; j++)
                    acc[i][j] = __builtin_amdgcn_mfma_f32_16x16x32_bf16(af[i], bfr[j], acc[i][j], 0, 0, 0);
        }
    }

    #pragma unroll
    for (int i = 0; i < 4; i++) {
        #pragma unroll
        for (int j = 0; j < 4; j++) {
            int n = tileN + wn + j * 16 + ln;
            float bv = bias[n];
            #pragma unroll
            for (int r = 0; r < 4; r++) {
                int m = tileM + wm + i * 16 + quad * 4 + r;
                float v = acc[i][j][r] + bv;
                if (OUT_BF16)
                    ((u16*)Cout)[(size_t)m * N + n] = f2bf(v);
                else
                    ((float*)Cout)[(size_t)m * N + n] = v;
            }
        }
    }
}

// ---------------- RoPE + split qkv (bf16 in, bf16 out) ----------------
// qkv bf16 (S, NQKV) laid out per position as (NKV=8, 6, 128): [q0..q3, k, v].
__global__ __launch_bounds__(128) void rope_split_kernel(
    const u16* __restrict__ qkv, const int* __restrict__ positions,
    u16* __restrict__ qb_o, u16* __restrict__ kb_o, u16* __restrict__ vb_o)
{
    const int d   = threadIdx.x;     // 0..127
    const int pos = blockIdx.x;      // 0..S-1
    const int hy  = blockIdx.y;      // 0..47
    const float p = (float)positions[pos];

    if (hy >= NHEADS + NKVH) {               // v copy
        int kv = hy - NHEADS - NKVH;
        const u16* src = qkv + (size_t)pos * NQKV + (kv * 6 + 5) * HDIM;
        vb_o[((size_t)kv * S_LEN + pos) * HDIM + d] = src[d];
        return;
    }
    const u16* src;
    u16* dst;
    if (hy < NHEADS) {                        // q head
        int kv = hy >> 2, qi = hy & 3;
        src = qkv + (size_t)pos * NQKV + (kv * 6 + qi) * HDIM;
        dst = qb_o + ((size_t)hy * S_LEN + pos) * HDIM;
    } else {                                  // k head
        int kv = hy - NHEADS;
        src = qkv + (size_t)pos * NQKV + (kv * 6 + 4) * HDIM;
        dst = kb_o + ((size_t)kv * S_LEN + pos) * HDIM;
    }
    int d2 = d & 63;
    float inv = expf(-(float)d2 * (13.815510557964274f / 64.0f)); // 1e6^(-d2/64)
    float fr = p * inv;
    float s, c;
    sincosf(fr, &s, &c);
    float x1 = bf2f(src[d2]);
    float x2 = bf2f(src[d2 + 64]);
    float o = (d < 64) ? (x1 * c - x2 * s) : (x2 * c + x1 * s);
    dst[d] = f2bf(o);
}

// ---------------- blocksparse flash attention ----------------
// grid (S/64, NH); block 256 (4 waves). Wave w owns query rows w*16..w*16+15.
#define LDK 136   // 128+8
#define LDV 72    // 64+8
__global__ __launch_bounds__(256) void attn_bs_kernel(
    const u16* __restrict__ Q,   // (NH, S, HD) bf16
    const u16* __restrict__ K,   // (NKV, S, HD)
    const u16* __restrict__ V,   // (NKV, S, HD)
    u16* __restrict__ O)         // (S, NH*HD) bf16
{
    __shared__ u16 Qs[64][LDK];
    __shared__ u16 Ks[64][LDK];
    __shared__ u16 Vt[128][LDV];
    __shared__ u16 Ps[4][16][LDV];

    const int qb = blockIdx.x;
    const int h  = blockIdx.y;
    const int kv = h >> 2;
    const int tid  = threadIdx.x;
    const int w    = tid >> 6;
    const int lane = tid & 63;
    const int ln   = lane & 15;
    const int quad = lane >> 4;

    // stage Q tile (64 x 128)
    const u16* Qg = Q + ((size_t)h * S_LEN + qb * 64) * HDIM;
    {
        int col = (tid & 15) * 8;
        #pragma unroll
        for (int p = 0; p < 4; p++) {
            int row = p * 16 + (tid >> 4);
            *(uint4*)(&Qs[row][col]) = *(const uint4*)(Qg + row * HDIM + col);
        }
    }

    f32x4 oacc[8];
    #pragma unroll
    for (int n = 0; n < 8; n++) { f32x4 z = {0.f,0.f,0.f,0.f}; oacc[n] = z; }
    float mrow[4] = {-1e30f, -1e30f, -1e30f, -1e30f};
    float lrow[4] = {0.f, 0.f, 0.f, 0.f};

    for (int kb = 0; kb <= qb; kb++) {
        bool sel = (qb - kb < 16) || (((kb + h + 1) & 7) == 0);
        if (!sel) continue;

        __syncthreads();   // protect previous iteration's LDS reads
        const u16* Kg = K + ((size_t)kv * S_LEN + kb * 64) * HDIM;
        const u16* Vg = V + ((size_t)kv * S_LEN + kb * 64) * HDIM;
        {
            int col = (tid & 15) * 8;
            #pragma unroll
            for (int p = 0; p < 4; p++) {
                int row = p * 16 + (tid >> 4);
                *(uint4*)(&Ks[row][col]) = *(const uint4*)(Kg + row * HDIM + col);
            }
            // V staged transposed: Vt[dim][key]
            int key = tid & 63;
            int dbase = (tid >> 6) * 32;
            #pragma unroll
            for (int p = 0; p < 4; p++) {
                int d0 = dbase + p * 8;
                uint4 vv = *(const uint4*)(Vg + key * HDIM + d0);
                const u16* pv = (const u16*)&vv;
                #pragma unroll
                for (int jj = 0; jj < 8; jj++) Vt[d0 + jj][key] = pv[jj];
            }
        }
        __syncthreads();

        // S = Q K^T  (wave's 16 rows x 64 keys)
        f32x4 sacc[4];
        #pragma unroll
        for (int jj = 0; jj < 4; jj++) { f32x4 z = {0.f,0.f,0.f,0.f}; sacc[jj] = z; }
        #pragma unroll
        for (int ks = 0; ks < 4; ks++) {
            bf16x8 aq = *(const bf16x8*)(&Qs[w * 16 + ln][ks * 32 + quad * 8]);
            #pragma unroll
            for (int jj = 0; jj < 4; jj++) {
                bf16x8 bk = *(const bf16x8*)(&Ks[jj * 16 + ln][ks * 32 + quad * 8]);
                sacc[jj] = __builtin_amdgcn_mfma_f32_16x16x32_bf16(aq, bk, sacc[jj], 0, 0, 0);
            }
        }

        // scale + diagonal causal mask + online softmax; write P to LDS
        #pragma unroll
        for (int r = 0; r < 4; r++) {
            float pv[4];
            float mx = -1e30f;
            const int qrow = w * 16 + quad * 4 + r;
            #pragma unroll
            for (int jj = 0; jj < 4; jj++) {
                float s = sacc[jj][r] * ATT_SCALE;
                if (kb == qb && (jj * 16 + ln) > qrow) s = -1e30f;
                pv[jj] = s;
                mx = fmaxf(mx, s);
            }
            #pragma unroll
            for (int off = 1; off < 16; off <<= 1)
                mx = fmaxf(mx, __shfl_xor(mx, off, 64));
            float mnew  = fmaxf(mrow[r], mx);
            float alpha = __expf(mrow[r] - mnew);
            float sum = 0.f;
            #pragma unroll
            for (int jj = 0; jj < 4; jj++) {
                float pe = __expf(pv[jj] - mnew);
                pv[jj] = pe;
                sum += pe;
            }
            #pragma unroll
            for (int off = 1; off < 16; off <<= 1)
                sum += __shfl_xor(sum, off, 64);
            lrow[r] = lrow[r] * alpha + sum;
            mrow[r] = mnew;
            #pragma unroll
            for (int n = 0; n < 8; n++) oacc[n][r] *= alpha;
            #pragma unroll
            for (int jj = 0; jj < 4; jj++)
                Ps[w][quad * 4 + r][jj * 16 + ln] = f2bf(pv[jj]);
        }
        __syncthreads();   // P LDS round-trip visibility

        // O += P V   (P: 16x64 A-layout; V via Vt: B[n=dim][k=key])
        #pragma unroll
        for (int kk = 0; kk < 2; kk++) {
            bf16x8 ap = *(const bf16x8*)(&Ps[w][ln][kk * 32 + quad * 8]);
            #pragma unroll
            for (int n = 0; n < 8; n++) {
                bf16x8 bv = *(const bf16x8*)(&Vt[n * 16 + ln][kk * 32 + quad * 8]);
                oacc[n] = __builtin_amdgcn_mfma_f32_16x16x32_bf16(ap, bv, oacc[n], 0, 0, 0);
            }
        }
    }

    // epilogue: O /= l, store bf16 (S, NH*HD)
    #pragma unroll
    for (int n = 0; n < 8; n++) {
        #pragma unroll
        for (int r = 0; r < 4; r++) {
            int row = w * 16 + quad * 4 + r;
            int pos = qb * 64 + row;
            float o = oacc[n][r] / lrow[r];
            O[(size_t)pos * (NHEADS * HDIM) + h * HDIM + n * 16 + ln] = f2bf(o);
        }
    }
}

// ---------------- launch ----------------
extern "C" void kernel_launch(void* const* d_in, const int* in_sizes, int n_in,
                              void* d_out, int out_size, void* d_ws, size_t ws_size,
                              hipStream_t stream) {
    const int*   positions = (const int*)d_in[0];
    const float* hidden    = (const float*)d_in[1];
    const float* w_qkv     = (const float*)d_in[2];
    const float* b_qkv     = (const float*)d_in[3];
    const float* w_dense   = (const float*)d_in[4];
    const float* b_dense   = (const float*)d_in[5];
    float* out = (float*)d_out;

    char* ws = (char*)d_ws;
    u16* ws_h    = (u16*)(ws);                    // 2048*4096*2   = 16,777,216
    u16* ws_wqkv = (u16*)(ws + 16777216);         // 6144*4096*2  = 50,331,648
    u16* ws_wd   = (u16*)(ws + 67108864);         // 4096*4096*2  = 33,554,432
    u16* ws_qkv  = (u16*)(ws + 100663296);        // 2048*6144*2  = 25,165,824 (bf16)
    u16* ws_q    = (u16*)(ws + 125829120);        // 32*2048*128*2= 16,777,216
    u16* ws_k    = (u16*)(ws + 142606336);        // 8*2048*128*2 =  4,194,304
    u16* ws_v    = (u16*)(ws + 146800640);        //               =  4,194,304
    u16* ws_attn = (u16*)(ws + 150994944);        // 2048*4096*2  = 16,777,216

    cvt_bf16_kernel<<<1024, 256, 0, stream>>>(hidden,  ws_h,    (S_LEN * HID) / 4);
    cvt_bf16_kernel<<<2048, 256, 0, stream>>>(w_qkv,   ws_wqkv, (NQKV * HID) / 4);
    cvt_bf16_kernel<<<2048, 256, 0, stream>>>(w_dense, ws_wd,   (HID * HID) / 4);

    gemm_bt_kernel<true><<<dim3(NQKV / BN, S_LEN / BM), 256, 0, stream>>>(
        ws_h, ws_wqkv, b_qkv, ws_qkv, S_LEN, NQKV, HID);

    rope_split_kernel<<<dim3(S_LEN, NHEADS + 2 * NKVH), 128, 0, stream>>>(
        ws_qkv, positions, ws_q, ws_k, ws_v);

    attn_bs_kernel<<<dim3(S_LEN / 64, NHEADS), 256, 0, stream>>>(ws_q, ws_k, ws_v, ws_attn);

    gemm_bt_kernel<false><<<dim3(HID / BN, S_LEN / BM), 256, 0, stream>>>(
        ws_attn, ws_wd, b_dense, out, S_LEN, HID, HID);
}

// Round 4
// 579.774 us; speedup vs baseline: 1.1753x; 1.1011x over previous
//
#include <hip/hip_runtime.h>

#define S_LEN   2048
#define HID     4096
#define NHEADS  32
#define NKVH    8
#define HDIM    128
#define NQKV    6144          // NKV*(QPK+2)*HD = 8*6*128
#define ATT_SCALE (1.0f/128.0f)

typedef unsigned short u16;
typedef __attribute__((ext_vector_type(8))) __bf16 bf16x8;
typedef __attribute__((ext_vector_type(4))) float  f32x4;

__device__ __forceinline__ u16 f2bf(float f) {
    union { float f; unsigned u; } x; x.f = f;
    unsigned u = x.u;
    u += 0x7fffu + ((u >> 16) & 1u);   // round-to-nearest-even
    return (u16)(u >> 16);
}
__device__ __forceinline__ float bf2f(u16 v) {
    union { unsigned u; float f; } x; x.u = ((unsigned)v) << 16; return x.f;
}

// ---------------- fp32 -> bf16 conversion ----------------
__global__ __launch_bounds__(256) void cvt_bf16_kernel(const float* __restrict__ in,
                                                       u16* __restrict__ out, int n4) {
    int stride = gridDim.x * blockDim.x;
    for (int i = blockIdx.x * blockDim.x + threadIdx.x; i < n4; i += stride) {
        float4 v = *(const float4*)(in + (size_t)i * 4);
        ushort4 o = make_ushort4(f2bf(v.x), f2bf(v.y), f2bf(v.z), f2bf(v.w));
        *(ushort4*)(out + (size_t)i * 4) = o;
    }
}

// ---------------- bf16 GEMM:  C(MxN) = A(MxK) * B(NxK)^T + bias(N) ----------------
// Async-pipelined: 128x128 tile, BK=32, DOUBLE-buffered LDS (32 KB total),
// ONE barrier per K-iter; global_load_lds prefetch for tile k+1 issued right
// after the barrier that made tile k resident, so the vmcnt(0) drain at the
// next barrier is overlapped by a full compute phase.
// XOR swizzle: physical 16B chunk = logical ^ ((row>>1)&3)  (<=2-way = free).
#define BM 128
#define BN 128
#define BK 32

template <bool OUT_BF16>
__global__ __launch_bounds__(256) void gemm_bt_kernel(
    const u16* __restrict__ A,   // M x K  bf16
    const u16* __restrict__ B,   // N x K  bf16
    const float* __restrict__ bias, // N
    void* __restrict__ Cout,     // M x N  (fp32 or bf16)
    int M, int N, int K)
{
    __shared__ u16 Alds[2][BM][BK];   // 8 KB per buffer per array -> 32 KB total
    __shared__ u16 Blds[2][BN][BK];

    const int tid  = threadIdx.x;
    const int wid  = tid >> 6;
    const int lane = tid & 63;
    const int ln   = lane & 15;
    const int quad = lane >> 4;
    const int wm   = (wid >> 1) * 64;
    const int wn   = (wid & 1) * 64;
    const int tileM = blockIdx.y * BM;
    const int tileN = blockIdx.x * BN;

    // staging: one global_load_lds covers 16 rows (64 lanes x 16B over 64B rows).
    // lane writes physical chunk (lane&3) of row (lane>>2); to realize
    // phys = logical ^ ((row>>1)&3), lane fetches logical chunk (lane&3)^((srow>>1)&3).
    const int srow = lane >> 2;                          // 0..15
    const int scol = ((lane & 3) ^ ((srow >> 1) & 3)) * 8; // source column (elems)

    f32x4 acc[4][4];
    #pragma unroll
    for (int i = 0; i < 4; i++)
        #pragma unroll
        for (int j = 0; j < 4; j++) {
            f32x4 z = {0.f, 0.f, 0.f, 0.f};
            acc[i][j] = z;
        }

    auto stage = [&](int k, int buf) {
        const int k0 = k * BK;
        #pragma unroll
        for (int p = 0; p < 2; p++) {
            int r = p * 64 + wid * 16;                   // wave-uniform row base
            const u16* ga = A + (size_t)(tileM + r + srow) * K + k0 + scol;
            const u16* gb = B + (size_t)(tileN + r + srow) * K + k0 + scol;
            __builtin_amdgcn_global_load_lds(
                (const __attribute__((address_space(1))) void*)ga,
                (__attribute__((address_space(3))) void*)&Alds[buf][r][0], 16, 0, 0);
            __builtin_amdgcn_global_load_lds(
                (const __attribute__((address_space(1))) void*)gb,
                (__attribute__((address_space(3))) void*)&Blds[buf][r][0], 16, 0, 0);
        }
    };

    const int nIter = K / BK;
    stage(0, 0);                                         // prologue prefetch

    const int pc = (quad ^ ((ln >> 1) & 3)) * 8;         // read-side physical column

    for (int k = 0; k < nIter; k++) {
        const int buf = k & 1;
        __syncthreads();            // drains vmcnt -> tile k resident; prior reads of buf^1 done
        if (k + 1 < nIter) stage(k + 1, buf ^ 1);

        bf16x8 af[4], bfr[4];
        #pragma unroll
        for (int i = 0; i < 4; i++)
            af[i] = *(const bf16x8*)(&Alds[buf][wm + i * 16 + ln][pc]);
        #pragma unroll
        for (int j = 0; j < 4; j++)
            bfr[j] = *(const bf16x8*)(&Blds[buf][wn + j * 16 + ln][pc]);
        #pragma unroll
        for (int i = 0; i < 4; i++)
            #pragma unroll
            for (int j = 0; j < 4; j++)
                acc[i][j] = __builtin_amdgcn_mfma_f32_16x16x32_bf16(af[i], bfr[j], acc[i][j], 0, 0, 0);
    }

    #pragma unroll
    for (int i = 0; i < 4; i++) {
        #pragma unroll
        for (int j = 0; j < 4; j++) {
            int n = tileN + wn + j * 16 + ln;
            float bv = bias[n];
            #pragma unroll
            for (int r = 0; r < 4; r++) {
                int m = tileM + wm + i * 16 + quad * 4 + r;
                float v = acc[i][j][r] + bv;
                if (OUT_BF16)
                    ((u16*)Cout)[(size_t)m * N + n] = f2bf(v);
                else
                    ((float*)Cout)[(size_t)m * N + n] = v;
            }
        }
    }
}

// ---------------- RoPE + split qkv (bf16 in, bf16 out) ----------------
// qkv bf16 (S, NQKV) laid out per position as (NKV=8, 6, 128): [q0..q3, k, v].
__global__ __launch_bounds__(128) void rope_split_kernel(
    const u16* __restrict__ qkv, const int* __restrict__ positions,
    u16* __restrict__ qb_o, u16* __restrict__ kb_o, u16* __restrict__ vb_o)
{
    const int d   = threadIdx.x;     // 0..127
    const int pos = blockIdx.x;      // 0..S-1
    const int hy  = blockIdx.y;      // 0..47
    const float p = (float)positions[pos];

    if (hy >= NHEADS + NKVH) {               // v copy
        int kv = hy - NHEADS - NKVH;
        const u16* src = qkv + (size_t)pos * NQKV + (kv * 6 + 5) * HDIM;
        vb_o[((size_t)kv * S_LEN + pos) * HDIM + d] = src[d];
        return;
    }
    const u16* src;
    u16* dst;
    if (hy < NHEADS) {                        // q head
        int kv = hy >> 2, qi = hy & 3;
        src = qkv + (size_t)pos * NQKV + (kv * 6 + qi) * HDIM;
        dst = qb_o + ((size_t)hy * S_LEN + pos) * HDIM;
    } else {                                  // k head
        int kv = hy - NHEADS;
        src = qkv + (size_t)pos * NQKV + (kv * 6 + 4) * HDIM;
        dst = kb_o + ((size_t)kv * S_LEN + pos) * HDIM;
    }
    int d2 = d & 63;
    float inv = expf(-(float)d2 * (13.815510557964274f / 64.0f)); // 1e6^(-d2/64)
    float fr = p * inv;
    float s, c;
    sincosf(fr, &s, &c);
    float x1 = bf2f(src[d2]);
    float x2 = bf2f(src[d2 + 64]);
    float o = (d < 64) ? (x1 * c - x2 * s) : (x2 * c + x1 * s);
    dst[d] = f2bf(o);
}

// ---------------- blocksparse flash attention ----------------
// grid (S/64, NH); block 256 (4 waves). Wave w owns query rows w*16..w*16+15.
#define LDK 136   // 128+8
#define LDV 72    // 64+8
__global__ __launch_bounds__(256) void attn_bs_kernel(
    const u16* __restrict__ Q,   // (NH, S, HD) bf16
    const u16* __restrict__ K,   // (NKV, S, HD)
    const u16* __restrict__ V,   // (NKV, S, HD)
    u16* __restrict__ O)         // (S, NH*HD) bf16
{
    __shared__ u16 Qs[64][LDK];
    __shared__ u16 Ks[64][LDK];
    __shared__ u16 Vt[128][LDV];
    __shared__ u16 Ps[4][16][LDV];

    const int qb = blockIdx.x;
    const int h  = blockIdx.y;
    const int kv = h >> 2;
    const int tid  = threadIdx.x;
    const int w    = tid >> 6;
    const int lane = tid & 63;
    const int ln   = lane & 15;
    const int quad = lane >> 4;

    // stage Q tile (64 x 128)
    const u16* Qg = Q + ((size_t)h * S_LEN + qb * 64) * HDIM;
    {
        int col = (tid & 15) * 8;
        #pragma unroll
        for (int p = 0; p < 4; p++) {
            int row = p * 16 + (tid >> 4);
            *(uint4*)(&Qs[row][col]) = *(const uint4*)(Qg + row * HDIM + col);
        }
    }

    f32x4 oacc[8];
    #pragma unroll
    for (int n = 0; n < 8; n++) { f32x4 z = {0.f,0.f,0.f,0.f}; oacc[n] = z; }
    float mrow[4] = {-1e30f, -1e30f, -1e30f, -1e30f};
    float lrow[4] = {0.f, 0.f, 0.f, 0.f};

    for (int kb = 0; kb <= qb; kb++) {
        bool sel = (qb - kb < 16) || (((kb + h + 1) & 7) == 0);
        if (!sel) continue;

        __syncthreads();   // protect previous iteration's LDS reads
        const u16* Kg = K + ((size_t)kv * S_LEN + kb * 64) * HDIM;
        const u16* Vg = V + ((size_t)kv * S_LEN + kb * 64) * HDIM;
        {
            int col = (tid & 15) * 8;
            #pragma unroll
            for (int p = 0; p < 4; p++) {
                int row = p * 16 + (tid >> 4);
                *(uint4*)(&Ks[row][col]) = *(const uint4*)(Kg + row * HDIM + col);
            }
            // V staged transposed: Vt[dim][key]
            int key = tid & 63;
            int dbase = (tid >> 6) * 32;
            #pragma unroll
            for (int p = 0; p < 4; p++) {
                int d0 = dbase + p * 8;
                uint4 vv = *(const uint4*)(Vg + key * HDIM + d0);
                const u16* pv = (const u16*)&vv;
                #pragma unroll
                for (int jj = 0; jj < 8; jj++) Vt[d0 + jj][key] = pv[jj];
            }
        }
        __syncthreads();

        // S = Q K^T  (wave's 16 rows x 64 keys)
        f32x4 sacc[4];
        #pragma unroll
        for (int jj = 0; jj < 4; jj++) { f32x4 z = {0.f,0.f,0.f,0.f}; sacc[jj] = z; }
        #pragma unroll
        for (int ks = 0; ks < 4; ks++) {
            bf16x8 aq = *(const bf16x8*)(&Qs[w * 16 + ln][ks * 32 + quad * 8]);
            #pragma unroll
            for (int jj = 0; jj < 4; jj++) {
                bf16x8 bk = *(const bf16x8*)(&Ks[jj * 16 + ln][ks * 32 + quad * 8]);
                sacc[jj] = __builtin_amdgcn_mfma_f32_16x16x32_bf16(aq, bk, sacc[jj], 0, 0, 0);
            }
        }

        // scale + diagonal causal mask + online softmax; write P to LDS
        #pragma unroll
        for (int r = 0; r < 4; r++) {
            float pv[4];
            float mx = -1e30f;
            const int qrow = w * 16 + quad * 4 + r;
            #pragma unroll
            for (int jj = 0; jj < 4; jj++) {
                float s = sacc[jj][r] * ATT_SCALE;
                if (kb == qb && (jj * 16 + ln) > qrow) s = -1e30f;
                pv[jj] = s;
                mx = fmaxf(mx, s);
            }
            #pragma unroll
            for (int off = 1; off < 16; off <<= 1)
                mx = fmaxf(mx, __shfl_xor(mx, off, 64));
            float mnew  = fmaxf(mrow[r], mx);
            float alpha = __expf(mrow[r] - mnew);
            float sum = 0.f;
            #pragma unroll
            for (int jj = 0; jj < 4; jj++) {
                float pe = __expf(pv[jj] - mnew);
                pv[jj] = pe;
                sum += pe;
            }
            #pragma unroll
            for (int off = 1; off < 16; off <<= 1)
                sum += __shfl_xor(sum, off, 64);
            lrow[r] = lrow[r] * alpha + sum;
            mrow[r] = mnew;
            #pragma unroll
            for (int n = 0; n < 8; n++) oacc[n][r] *= alpha;
            #pragma unroll
            for (int jj = 0; jj < 4; jj++)
                Ps[w][quad * 4 + r][jj * 16 + ln] = f2bf(pv[jj]);
        }
        __syncthreads();   // P LDS round-trip visibility

        // O += P V   (P: 16x64 A-layout; V via Vt: B[n=dim][k=key])
        #pragma unroll
        for (int kk = 0; kk < 2; kk++) {
            bf16x8 ap = *(const bf16x8*)(&Ps[w][ln][kk * 32 + quad * 8]);
            #pragma unroll
            for (int n = 0; n < 8; n++) {
                bf16x8 bv = *(const bf16x8*)(&Vt[n * 16 + ln][kk * 32 + quad * 8]);
                oacc[n] = __builtin_amdgcn_mfma_f32_16x16x32_bf16(ap, bv, oacc[n], 0, 0, 0);
            }
        }
    }

    // epilogue: O /= l, store bf16 (S, NH*HD)
    #pragma unroll
    for (int n = 0; n < 8; n++) {
        #pragma unroll
        for (int r = 0; r < 4; r++) {
            int row = w * 16 + quad * 4 + r;
            int pos = qb * 64 + row;
            float o = oacc[n][r] / lrow[r];
            O[(size_t)pos * (NHEADS * HDIM) + h * HDIM + n * 16 + ln] = f2bf(o);
        }
    }
}

// ---------------- launch ----------------
extern "C" void kernel_launch(void* const* d_in, const int* in_sizes, int n_in,
                              void* d_out, int out_size, void* d_ws, size_t ws_size,
                              hipStream_t stream) {
    const int*   positions = (const int*)d_in[0];
    const float* hidden    = (const float*)d_in[1];
    const float* w_qkv     = (const float*)d_in[2];
    const float* b_qkv     = (const float*)d_in[3];
    const float* w_dense   = (const float*)d_in[4];
    const float* b_dense   = (const float*)d_in[5];
    float* out = (float*)d_out;

    char* ws = (char*)d_ws;
    u16* ws_h    = (u16*)(ws);                    // 2048*4096*2   = 16,777,216
    u16* ws_wqkv = (u16*)(ws + 16777216);         // 6144*4096*2  = 50,331,648
    u16* ws_wd   = (u16*)(ws + 67108864);         // 4096*4096*2  = 33,554,432
    u16* ws_qkv  = (u16*)(ws + 100663296);        // 2048*6144*2  = 25,165,824 (bf16)
    u16* ws_q    = (u16*)(ws + 125829120);        // 32*2048*128*2= 16,777,216
    u16* ws_k    = (u16*)(ws + 142606336);        // 8*2048*128*2 =  4,194,304
    u16* ws_v    = (u16*)(ws + 146800640);        //               =  4,194,304
    u16* ws_attn = (u16*)(ws + 150994944);        // 2048*4096*2  = 16,777,216

    cvt_bf16_kernel<<<1024, 256, 0, stream>>>(hidden,  ws_h,    (S_LEN * HID) / 4);
    cvt_bf16_kernel<<<2048, 256, 0, stream>>>(w_qkv,   ws_wqkv, (NQKV * HID) / 4);
    cvt_bf16_kernel<<<2048, 256, 0, stream>>>(w_dense, ws_wd,   (HID * HID) / 4);

    gemm_bt_kernel<true><<<dim3(NQKV / BN, S_LEN / BM), 256, 0, stream>>>(
        ws_h, ws_wqkv, b_qkv, ws_qkv, S_LEN, NQKV, HID);

    rope_split_kernel<<<dim3(S_LEN, NHEADS + 2 * NKVH), 128, 0, stream>>>(
        ws_qkv, positions, ws_q, ws_k, ws_v);

    attn_bs_kernel<<<dim3(S_LEN / 64, NHEADS), 256, 0, stream>>>(ws_q, ws_k, ws_v, ws_attn);

    gemm_bt_kernel<false><<<dim3(HID / BN, S_LEN / BM), 256, 0, stream>>>(
        ws_attn, ws_wd, b_dense, out, S_LEN, HID, HID);
}